// Round 1
// baseline (907.207 us; speedup 1.0000x reference)
//
#include <hip/hip_runtime.h>
#include <cstdint>
#include <cstddef>

typedef unsigned short u16;
typedef unsigned int u32;
typedef short short8 __attribute__((ext_vector_type(8)));
typedef float f32x4 __attribute__((ext_vector_type(4)));

__device__ __forceinline__ u16 f2bf(float f) {
  unsigned u = __float_as_uint(f);
  u += 0x7fffu + ((u >> 16) & 1u);
  return (u16)(u >> 16);
}
__device__ __forceinline__ float bf2f(u16 h) {
  return __uint_as_float(((unsigned)h) << 16);
}
__device__ __forceinline__ u32 pack_bf2(float lo, float hi) {
  return ((u32)f2bf(hi) << 16) | (u32)f2bf(lo);
}

typedef const __attribute__((address_space(1))) unsigned int gu32_t;
typedef __attribute__((address_space(3))) unsigned int su32_t;
__device__ __forceinline__ void gl2lds16(const void* g, void* l) {
  __builtin_amdgcn_global_load_lds((gu32_t*)g, (su32_t*)l, 16, 0, 0);
}

__device__ __forceinline__ f32x4 mfma_bf16(short8 a, short8 b, f32x4 c) {
  return __builtin_amdgcn_mfma_f32_16x16x32_bf16(a, b, c, 0, 0, 0);
}

// ---------------- elementwise fp32 -> bf16 ----------------
__global__ __launch_bounds__(256) void f32_to_bf16_kernel(
    const float* __restrict__ x, u16* __restrict__ y, int n) {
  int i = (blockIdx.x * 256 + threadIdx.x) * 4;
  if (i + 3 < n) {
    float4 v = *(const float4*)(x + i);
    ushort4 o;
    o.x = f2bf(v.x); o.y = f2bf(v.y); o.z = f2bf(v.z); o.w = f2bf(v.w);
    *(ushort4*)(y + i) = o;
  }
}

// ---------------- W [K][N] fp32 -> Wt [N][K] bf16 (tiled transpose) ----------------
__global__ __launch_bounds__(256) void transpose_w_kernel(
    const float* __restrict__ W, u16* __restrict__ Wt, int K, int N) {
  __shared__ float tile[32][33];
  int n0 = blockIdx.x * 32, k0 = blockIdx.y * 32;
  int tx = threadIdx.x, ty = threadIdx.y;
#pragma unroll
  for (int j = 0; j < 4; ++j)
    tile[ty + j * 8][tx] = W[(size_t)(k0 + ty + j * 8) * N + n0 + tx];
  __syncthreads();
#pragma unroll
  for (int j = 0; j < 4; ++j)
    Wt[(size_t)(n0 + ty + j * 8) * K + k0 + tx] = f2bf(tile[tx][ty + j * 8]);
}

// ---------------- GEMM 256x256 tile, BK=32, 4-slot LDS ring, counted vmcnt ---------
// C[M][ldc] = A[M][K] @ Bt[N][K]^T (bf16 in, fp32 acc). 512 threads = 8 waves (2Mx4N).
// LDS: 4 ring slots x (As[256][32] + Bs[256][32]) = 128 KiB. Swizzle: logical chunk c
// of row r stored at physical chunk c ^ ((r>>1)&3) -> 2-way bank alias (free).
// Pipeline: stage tile t+3, s_waitcnt vmcnt(12) (3 tiles in flight, NEVER drains in
// main loop), raw s_barrier, 2x16 MFMA with setprio(1). Epilogue peels vmcnt 8/4/0.
__device__ __forceinline__ void tile_compute(const u16* __restrict__ as,
                                             const u16* __restrict__ bs,
                                             f32x4 (&acc)[8][4],
                                             int arow, int brow, int qoff) {
  short8 bfr[4], afr[4];
#pragma unroll
  for (int n = 0; n < 4; ++n)
    bfr[n] = *(const short8*)&bs[(brow + n * 16) * 32 + qoff];
#pragma unroll
  for (int m = 0; m < 4; ++m)
    afr[m] = *(const short8*)&as[(arow + m * 16) * 32 + qoff];
  __builtin_amdgcn_s_setprio(1);
#pragma unroll
  for (int m = 0; m < 4; ++m)
#pragma unroll
    for (int n = 0; n < 4; ++n)
      acc[m][n] = mfma_bf16(afr[m], bfr[n], acc[m][n]);
  __builtin_amdgcn_s_setprio(0);
#pragma unroll
  for (int m = 0; m < 4; ++m)
    afr[m] = *(const short8*)&as[(arow + (4 + m) * 16) * 32 + qoff];
  __builtin_amdgcn_s_setprio(1);
#pragma unroll
  for (int m = 0; m < 4; ++m)
#pragma unroll
    for (int n = 0; n < 4; ++n)
      acc[4 + m][n] = mfma_bf16(afr[m], bfr[n], acc[4 + m][n]);
  __builtin_amdgcn_s_setprio(0);
}

#define STAGE256(slot_, ko_)                                     \
  do {                                                           \
    u16* as_ = &lds4[slot_][0][0];                               \
    u16* bs_ = &lds4[slot_][1][0];                               \
    gl2lds16(ap + (ko_), as_ + w * 512);                         \
    gl2lds16(ap + (size_t)128 * K + (ko_), as_ + 4096 + w * 512);\
    gl2lds16(bp + (ko_), bs_ + w * 512);                         \
    gl2lds16(bp + (size_t)128 * K + (ko_), bs_ + 4096 + w * 512);\
  } while (0)

#define SBAR()                          \
  do {                                  \
    asm volatile("" ::: "memory");      \
    __builtin_amdgcn_s_barrier();       \
    asm volatile("" ::: "memory");      \
  } while (0)

template <bool BF16OUT>
__global__ __launch_bounds__(512, 2) void gemm_bt_256(
    const u16* __restrict__ A, const u16* __restrict__ Bt,
    float* __restrict__ Cf, u16* __restrict__ Cb, int K, int ldc) {
  __shared__ alignas(16) u16 lds4[4][2][8192];  // 128 KiB
  const int tid = threadIdx.x;
  const int w = tid >> 6, lane = tid & 63;
  const int lq = lane & 15, qd = lane >> 4;
  const int wm = w >> 2, wn = w & 3;
  const int m0 = blockIdx.y * 256, n0 = blockIdx.x * 256;
  const int r4 = lane >> 2;
  const int csw = ((lane & 3) ^ ((lane >> 3) & 3)) * 8;  // staging source chunk
  const int qoff = (qd ^ ((lq >> 1) & 3)) * 8;           // reader swizzle
  const int arow = wm * 128 + lq, brow = wn * 64 + lq;

  f32x4 acc[8][4] = {};
  const u16* ap = A + ((size_t)(m0 + w * 16 + r4) * K + csw);
  const u16* bp = Bt + ((size_t)(n0 + w * 16 + r4) * K + csw);
  const int nt = K >> 5;

  STAGE256(0, 0);
  STAGE256(1, 32);
  STAGE256(2, 64);

  for (int t = 0; t + 3 < nt; ++t) {
    STAGE256((t + 3) & 3, (t + 3) * 32);
    asm volatile("s_waitcnt vmcnt(12)" ::: "memory");  // tile t retired; 3 in flight
    SBAR();
    tile_compute(&lds4[t & 3][0][0], &lds4[t & 3][1][0], acc, arow, brow, qoff);
    SBAR();  // WAR: all reads of slot done before next iteration restages it
  }
  asm volatile("s_waitcnt vmcnt(8)" ::: "memory");
  SBAR();
  tile_compute(&lds4[(nt - 3) & 3][0][0], &lds4[(nt - 3) & 3][1][0], acc, arow, brow, qoff);
  asm volatile("s_waitcnt vmcnt(4)" ::: "memory");
  SBAR();
  tile_compute(&lds4[(nt - 2) & 3][0][0], &lds4[(nt - 2) & 3][1][0], acc, arow, brow, qoff);
  asm volatile("s_waitcnt vmcnt(0)" ::: "memory");
  SBAR();
  tile_compute(&lds4[(nt - 1) & 3][0][0], &lds4[(nt - 1) & 3][1][0], acc, arow, brow, qoff);

#pragma unroll
  for (int m = 0; m < 8; ++m) {
    const int row = m0 + wm * 128 + m * 16 + qd * 4;
#pragma unroll
    for (int n = 0; n < 4; ++n) {
      const int col = n0 + wn * 64 + n * 16 + lq;
#pragma unroll
      for (int r = 0; r < 4; ++r) {
        if (BF16OUT)
          Cb[(size_t)(row + r) * ldc + col] = f2bf(acc[m][n][r]);
        else
          Cf[(size_t)(row + r) * ldc + col] = acc[m][n][r];
      }
    }
  }
}

#undef STAGE256

// ---------------- RoPE ----------------
__global__ __launch_bounds__(256) void rope_kernel(
    const u16* __restrict__ src, u16* __restrict__ dst,
    const int* __restrict__ pos_ids, int nh, int src_col0, int dst_ld, int total,
    float scale) {
  int idx = blockIdx.x * 256 + threadIdx.x;
  if (idx >= total) return;
  int i = idx & 63;
  int t = idx >> 6;
  int hh = t % nh;
  int m = t / nh;
  float pos = (float)pos_ids[m];
  float inv = exp2f(-(float)i * 0.20762050593046016f);
  float f = pos * inv;
  float c = cosf(f) * scale, s = sinf(f) * scale;
  const u16* sp = src + (size_t)m * 6144 + src_col0 + hh * 128;
  float x0 = bf2f(sp[i]);
  float x1 = bf2f(sp[i + 64]);
  u16* dp = dst + (size_t)m * dst_ld + hh * 128;
  dp[i] = f2bf(x0 * c - x1 * s);
  dp[i + 64] = f2bf(x1 * c + x0 * s);
}

// ---------------- V transpose ----------------
__global__ __launch_bounds__(256) void vt_kernel(
    const u16* __restrict__ src, u16* __restrict__ vt) {
  __shared__ u16 tile[32][33];
  int s0 = blockIdx.x * 32;
  int d0 = blockIdx.y * 32;
  int bz = blockIdx.z;
  int b = bz >> 3, kvh = bz & 7;
  int tx = threadIdx.x, ty = threadIdx.y;
#pragma unroll
  for (int j = 0; j < 4; ++j)
    tile[ty + j * 8][tx] =
        src[(size_t)(b * 2048 + s0 + ty + j * 8) * 6144 + 5120 + kvh * 128 + d0 + tx];
  __syncthreads();
#pragma unroll
  for (int j = 0; j < 4; ++j)
    vt[((size_t)(b * 8 + kvh) * 128 + d0 + ty + j * 8) * 2048 + s0 + tx] =
        tile[tx][ty + j * 8];
}

// ---------------- Flash attention (causal, GQA), transposed S/O, XOR-swizzled LDS ----
#define PS_LD 76
__global__ __launch_bounds__(256, 3) void flash_kernel(
    const u16* __restrict__ Q, const u16* __restrict__ K,
    const u16* __restrict__ Vt, u16* __restrict__ O) {
  __shared__ alignas(16) u16 Ks[64 * 128];     // [kv][d] swizzled
  __shared__ alignas(16) u16 Vs[128 * 64];     // [d][kv] swizzled
  __shared__ alignas(16) u16 Ps[4][32 * PS_LD];

  const int tid = threadIdx.x;
  const int w = tid >> 6, lane = tid & 63;
  const int lq = lane & 15, qd = lane >> 4;
  const int lq7 = lq & 7;
  const int bh = blockIdx.y;
  const int b = bh >> 5, h = bh & 31, kvh = h >> 2;
  const int q0 = (gridDim.x - 1 - blockIdx.x) * 128;

  short8 qf[2][4];
  {
    const u16* qp = Q + ((size_t)(b * 2048 + q0 + w * 32 + lq) * 4096 + h * 128 + qd * 8);
#pragma unroll
    for (int n = 0; n < 2; ++n)
#pragma unroll
      for (int ks = 0; ks < 4; ++ks)
        qf[n][ks] = *(const short8*)(qp + (size_t)n * 16 * 4096 + ks * 32);
  }

  f32x4 ot[2][8] = {};
  float mprev[2], lsum[2];
#pragma unroll
  for (int n = 0; n < 2; ++n) { mprev[n] = -1e30f; lsum[n] = 0.f; }

  const int rk = lane >> 4;
  const int pk = lane & 15;
  const int ckA = (pk ^ rk) * 8;
  const int ckB = (pk ^ (4 + rk)) * 8;
  const int rv = lane >> 3;
  const int cv = ((lane & 7) ^ rv) * 8;

  const int kv_end = q0 + 128;

  for (int kv0 = 0; kv0 < kv_end; kv0 += 64) {
    {
      const u16* kbase = K + ((size_t)(b * 2048 + kv0 + w * 16 + rk) * 1024) + kvh * 128;
#pragma unroll
      for (int i = 0; i < 4; ++i)
        gl2lds16(kbase + (size_t)(i * 4) * 1024 + ((i & 1) ? ckB : ckA),
                 &Ks[(w * 16 + i * 4) * 128]);
      const u16* vbase = Vt + ((size_t)((b * 8 + kvh) * 128 + w * 32 + rv) * 2048) + kv0 + cv;
#pragma unroll
      for (int i = 0; i < 4; ++i)
        gl2lds16(vbase + (size_t)(i * 8) * 2048, &Vs[(w * 32 + i * 8) * 64]);
    }
    __syncthreads();

    f32x4 st[4][2] = {};
#pragma unroll
    for (int ks = 0; ks < 4; ++ks) {
      short8 kf[4];
#pragma unroll
      for (int m = 0; m < 4; ++m)
        kf[m] = *(const short8*)&Ks[(m * 16 + lq) * 128 + ((ks * 4 + qd) ^ lq7) * 8];
#pragma unroll
      for (int m = 0; m < 4; ++m)
#pragma unroll
        for (int n = 0; n < 2; ++n)
          st[m][n] = mfma_bf16(kf[m], qf[n][ks], st[m][n]);
    }

    if (kv0 + 63 > q0) {
#pragma unroll
      for (int n = 0; n < 2; ++n) {
        const int qrow = q0 + w * 32 + n * 16 + lq;
#pragma unroll
        for (int m = 0; m < 4; ++m) {
          const int kvb = kv0 + m * 16 + qd * 4;
#pragma unroll
          for (int r = 0; r < 4; ++r)
            if (kvb + r > qrow) st[m][n][r] = -1e30f;
        }
      }
    }

#pragma unroll
    for (int n = 0; n < 2; ++n) {
      float t = st[0][n][0];
#pragma unroll
      for (int m = 0; m < 4; ++m)
#pragma unroll
        for (int r = 0; r < 4; ++r) t = fmaxf(t, st[m][n][r]);
      t = fmaxf(t, __shfl_xor(t, 16));
      t = fmaxf(t, __shfl_xor(t, 32));
      const float mnew = fmaxf(mprev[n], t);
      const float alpha = __expf(mprev[n] - mnew);
      mprev[n] = mnew;

      float rs = 0.f;
      u32 pk2[4][2];
#pragma unroll
      for (int m = 0; m < 4; ++m) {
        float p0 = __expf(st[m][n][0] - mnew);
        float p1 = __expf(st[m][n][1] - mnew);
        float p2 = __expf(st[m][n][2] - mnew);
        float p3 = __expf(st[m][n][3] - mnew);
        rs += (p0 + p1) + (p2 + p3);
        pk2[m][0] = pack_bf2(p0, p1);
        pk2[m][1] = pack_bf2(p2, p3);
      }
      rs += __shfl_xor(rs, 16);
      rs += __shfl_xor(rs, 32);
      lsum[n] = lsum[n] * alpha + rs;

      u16* pw = &Ps[w][(n * 16 + lq) * PS_LD + qd * 4];
#pragma unroll
      for (int m = 0; m < 4; ++m)
        *(uint2*)(pw + m * 16) = make_uint2(pk2[m][0], pk2[m][1]);

#pragma unroll
      for (int mt = 0; mt < 8; ++mt)
#pragma unroll
        for (int r = 0; r < 4; ++r) ot[n][mt][r] *= alpha;
    }

#pragma unroll
    for (int kst = 0; kst < 2; ++kst) {
      short8 bp[2];
#pragma unroll
      for (int n = 0; n < 2; ++n)
        bp[n] = *(const short8*)&Ps[w][(n * 16 + lq) * PS_LD + kst * 32 + qd * 8];
#pragma unroll
      for (int mt = 0; mt < 8; ++mt) {
        short8 av = *(const short8*)&Vs[(mt * 16 + lq) * 64 + ((kst * 4 + qd) ^ lq7) * 8];
#pragma unroll
        for (int n = 0; n < 2; ++n)
          ot[n][mt] = mfma_bf16(av, bp[n], ot[n][mt]);
      }
    }
    __syncthreads();
  }

#pragma unroll
  for (int n = 0; n < 2; ++n) {
    const float inv = 1.f / lsum[n];
    const size_t row = (size_t)(b * 2048 + q0 + w * 32 + n * 16 + lq);
    u16* op = O + row * 4096 + h * 128 + qd * 4;
#pragma unroll
    for (int mt = 0; mt < 8; ++mt) {
      u32 a = pack_bf2(ot[n][mt][0] * inv, ot[n][mt][1] * inv);
      u32 c = pack_bf2(ot[n][mt][2] * inv, ot[n][mt][3] * inv);
      *(uint2*)(op + mt * 16) = make_uint2(a, c);
    }
  }
}

// ---------------- launcher ----------------
extern "C" void kernel_launch(void* const* d_in, const int* in_sizes, int n_in,
                              void* d_out, int out_size, void* d_ws, size_t ws_size,
                              hipStream_t stream) {
  const float* hidden = (const float*)d_in[0];
  const int* pos = (const int*)d_in[1];
  const float* Wq = (const float*)d_in[2];
  const float* Wk = (const float*)d_in[3];
  const float* Wv = (const float*)d_in[4];
  const float* Wo = (const float*)d_in[5];
  float* out = (float*)d_out;

  char* ws = (char*)d_ws;
  u16* hbf   = (u16*)(ws);                       // 4096x4096 bf16     (32 MiB)
  u16* wqkvt = (u16*)(ws + 33554432ull);         // 6144x4096 bf16 B^T (48 MiB)
  u16* wot   = (u16*)(ws + 83886080ull);         // 4096x4096 bf16 B^T (32 MiB)
  u16* qkvbf = (u16*)(ws + 117440512ull);        // 4096x6144 bf16     (48 MiB)
  u16* qbf   = (u16*)(ws + 167772160ull);        // 4096x4096 bf16
  u16* kbf   = (u16*)(ws + 201326592ull);        // 4096x1024 bf16
  u16* vt    = (u16*)(ws + 209715200ull);        // 2x8x128x2048 bf16
  u16* obf   = (u16*)(ws + 218103808ull);        // 4096x4096 bf16 (ends at 240 MiB)

  f32_to_bf16_kernel<<<16384, 256, 0, stream>>>(hidden, hbf, 16777216);
  transpose_w_kernel<<<dim3(128, 128), dim3(32, 8), 0, stream>>>(Wq, wqkvt, 4096, 4096);
  transpose_w_kernel<<<dim3(32, 128), dim3(32, 8), 0, stream>>>(Wk, wqkvt + (size_t)4096 * 4096, 4096, 1024);
  transpose_w_kernel<<<dim3(32, 128), dim3(32, 8), 0, stream>>>(Wv, wqkvt + (size_t)5120 * 4096, 4096, 1024);
  transpose_w_kernel<<<dim3(128, 128), dim3(32, 8), 0, stream>>>(Wo, wot, 4096, 4096);

  gemm_bt_256<true><<<dim3(24, 16), 512, 0, stream>>>(hbf, wqkvt, nullptr, qkvbf, 4096, 6144);

  rope_kernel<<<32768, 256, 0, stream>>>(qkvbf, qbf, pos, 32, 0, 4096, 8388608, 0.08838834764831845f);
  rope_kernel<<<8192, 256, 0, stream>>>(qkvbf, kbf, pos, 8, 4096, 1024, 2097152, 1.0f);

  vt_kernel<<<dim3(64, 4, 16), dim3(32, 8), 0, stream>>>(qkvbf, vt);

  flash_kernel<<<dim3(16, 64), 256, 0, stream>>>(qbf, kbf, vt, obf);

  gemm_bt_256<false><<<dim3(16, 16), 512, 0, stream>>>(obf, wot, out, nullptr, 4096, 4096);
}

// Round 2
// 868.488 us; speedup vs baseline: 1.0446x; 1.0446x over previous
//
#include <hip/hip_runtime.h>
#include <cstdint>
#include <cstddef>

typedef unsigned short u16;
typedef unsigned int u32;
typedef short short8 __attribute__((ext_vector_type(8)));
typedef float f32x4 __attribute__((ext_vector_type(4)));

__device__ __forceinline__ u16 f2bf(float f) {
  unsigned u = __float_as_uint(f);
  u += 0x7fffu + ((u >> 16) & 1u);
  return (u16)(u >> 16);
}
__device__ __forceinline__ float bf2f(u16 h) {
  return __uint_as_float(((unsigned)h) << 16);
}
__device__ __forceinline__ u32 pack_bf2(float lo, float hi) {
  return ((u32)f2bf(hi) << 16) | (u32)f2bf(lo);
}

typedef const __attribute__((address_space(1))) unsigned int gu32_t;
typedef __attribute__((address_space(3))) unsigned int su32_t;
__device__ __forceinline__ void gl2lds16(const void* g, void* l) {
  __builtin_amdgcn_global_load_lds((gu32_t*)g, (su32_t*)l, 16, 0, 0);
}

__device__ __forceinline__ f32x4 mfma_bf16(short8 a, short8 b, f32x4 c) {
  return __builtin_amdgcn_mfma_f32_16x16x32_bf16(a, b, c, 0, 0, 0);
}

// ---------------- elementwise fp32 -> bf16 ----------------
__global__ __launch_bounds__(256) void f32_to_bf16_kernel(
    const float* __restrict__ x, u16* __restrict__ y, int n) {
  int i = (blockIdx.x * 256 + threadIdx.x) * 4;
  if (i + 3 < n) {
    float4 v = *(const float4*)(x + i);
    ushort4 o;
    o.x = f2bf(v.x); o.y = f2bf(v.y); o.z = f2bf(v.z); o.w = f2bf(v.w);
    *(ushort4*)(y + i) = o;
  }
}

// ---------------- W [K][N] fp32 -> Wt [N][K] bf16 (tiled transpose) ----------------
__global__ __launch_bounds__(256) void transpose_w_kernel(
    const float* __restrict__ W, u16* __restrict__ Wt, int K, int N) {
  __shared__ float tile[32][33];
  int n0 = blockIdx.x * 32, k0 = blockIdx.y * 32;
  int tx = threadIdx.x, ty = threadIdx.y;
#pragma unroll
  for (int j = 0; j < 4; ++j)
    tile[ty + j * 8][tx] = W[(size_t)(k0 + ty + j * 8) * N + n0 + tx];
  __syncthreads();
#pragma unroll
  for (int j = 0; j < 4; ++j)
    Wt[(size_t)(n0 + ty + j * 8) * K + k0 + tx] = f2bf(tile[tx][ty + j * 8]);
}

// ---------------- GEMM 256x256 tile, BK=32, 4-slot LDS ring, counted vmcnt ---------
__device__ __forceinline__ void tile_compute(const u16* __restrict__ as,
                                             const u16* __restrict__ bs,
                                             f32x4 (&acc)[8][4],
                                             int arow, int brow, int qoff) {
  short8 bfr[4], afr[4];
#pragma unroll
  for (int n = 0; n < 4; ++n)
    bfr[n] = *(const short8*)&bs[(brow + n * 16) * 32 + qoff];
#pragma unroll
  for (int m = 0; m < 4; ++m)
    afr[m] = *(const short8*)&as[(arow + m * 16) * 32 + qoff];
  __builtin_amdgcn_s_setprio(1);
#pragma unroll
  for (int m = 0; m < 4; ++m)
#pragma unroll
    for (int n = 0; n < 4; ++n)
      acc[m][n] = mfma_bf16(afr[m], bfr[n], acc[m][n]);
  __builtin_amdgcn_s_setprio(0);
#pragma unroll
  for (int m = 0; m < 4; ++m)
    afr[m] = *(const short8*)&as[(arow + (4 + m) * 16) * 32 + qoff];
  __builtin_amdgcn_s_setprio(1);
#pragma unroll
  for (int m = 0; m < 4; ++m)
#pragma unroll
    for (int n = 0; n < 4; ++n)
      acc[4 + m][n] = mfma_bf16(afr[m], bfr[n], acc[4 + m][n]);
  __builtin_amdgcn_s_setprio(0);
}

#define STAGE256(slot_, ko_)                                     \
  do {                                                           \
    u16* as_ = &lds4[slot_][0][0];                               \
    u16* bs_ = &lds4[slot_][1][0];                               \
    gl2lds16(ap + (ko_), as_ + w * 512);                         \
    gl2lds16(ap + (size_t)128 * K + (ko_), as_ + 4096 + w * 512);\
    gl2lds16(bp + (ko_), bs_ + w * 512);                         \
    gl2lds16(bp + (size_t)128 * K + (ko_), bs_ + 4096 + w * 512);\
  } while (0)

#define SBAR()                          \
  do {                                  \
    asm volatile("" ::: "memory");      \
    __builtin_amdgcn_s_barrier();       \
    asm volatile("" ::: "memory");      \
  } while (0)

template <bool BF16OUT>
__global__ __launch_bounds__(512, 2) void gemm_bt_256(
    const u16* __restrict__ A, const u16* __restrict__ Bt,
    float* __restrict__ Cf, u16* __restrict__ Cb, int K, int ldc) {
  __shared__ alignas(16) u16 lds4[4][2][8192];  // 128 KiB
  const int tid = threadIdx.x;
  const int w = tid >> 6, lane = tid & 63;
  const int lq = lane & 15, qd = lane >> 4;
  const int wm = w >> 2, wn = w & 3;
  const int m0 = blockIdx.y * 256, n0 = blockIdx.x * 256;
  const int r4 = lane >> 2;
  const int csw = ((lane & 3) ^ ((lane >> 3) & 3)) * 8;  // staging source chunk
  const int qoff = (qd ^ ((lq >> 1) & 3)) * 8;           // reader swizzle
  const int arow = wm * 128 + lq, brow = wn * 64 + lq;

  f32x4 acc[8][4] = {};
  const u16* ap = A + ((size_t)(m0 + w * 16 + r4) * K + csw);
  const u16* bp = Bt + ((size_t)(n0 + w * 16 + r4) * K + csw);
  const int nt = K >> 5;

  STAGE256(0, 0);
  STAGE256(1, 32);
  STAGE256(2, 64);

  for (int t = 0; t + 3 < nt; ++t) {
    STAGE256((t + 3) & 3, (t + 3) * 32);
    asm volatile("s_waitcnt vmcnt(12)" ::: "memory");  // tile t retired; 3 in flight
    SBAR();
    tile_compute(&lds4[t & 3][0][0], &lds4[t & 3][1][0], acc, arow, brow, qoff);
    SBAR();  // WAR: all reads of slot done before next iteration restages it
  }
  asm volatile("s_waitcnt vmcnt(8)" ::: "memory");
  SBAR();
  tile_compute(&lds4[(nt - 3) & 3][0][0], &lds4[(nt - 3) & 3][1][0], acc, arow, brow, qoff);
  asm volatile("s_waitcnt vmcnt(4)" ::: "memory");
  SBAR();
  tile_compute(&lds4[(nt - 2) & 3][0][0], &lds4[(nt - 2) & 3][1][0], acc, arow, brow, qoff);
  asm volatile("s_waitcnt vmcnt(0)" ::: "memory");
  SBAR();
  tile_compute(&lds4[(nt - 1) & 3][0][0], &lds4[(nt - 1) & 3][1][0], acc, arow, brow, qoff);

#pragma unroll
  for (int m = 0; m < 8; ++m) {
    const int row = m0 + wm * 128 + m * 16 + qd * 4;
#pragma unroll
    for (int n = 0; n < 4; ++n) {
      const int col = n0 + wn * 64 + n * 16 + lq;
#pragma unroll
      for (int r = 0; r < 4; ++r) {
        if (BF16OUT)
          Cb[(size_t)(row + r) * ldc + col] = f2bf(acc[m][n][r]);
        else
          Cf[(size_t)(row + r) * ldc + col] = acc[m][n][r];
      }
    }
  }
}

#undef STAGE256

// ---------------- RoPE ----------------
__global__ __launch_bounds__(256) void rope_kernel(
    const u16* __restrict__ src, u16* __restrict__ dst,
    const int* __restrict__ pos_ids, int nh, int src_col0, int dst_ld, int total,
    float scale) {
  int idx = blockIdx.x * 256 + threadIdx.x;
  if (idx >= total) return;
  int i = idx & 63;
  int t = idx >> 6;
  int hh = t % nh;
  int m = t / nh;
  float pos = (float)pos_ids[m];
  float inv = exp2f(-(float)i * 0.20762050593046016f);
  float f = pos * inv;
  float c = cosf(f) * scale, s = sinf(f) * scale;
  const u16* sp = src + (size_t)m * 6144 + src_col0 + hh * 128;
  float x0 = bf2f(sp[i]);
  float x1 = bf2f(sp[i + 64]);
  u16* dp = dst + (size_t)m * dst_ld + hh * 128;
  dp[i] = f2bf(x0 * c - x1 * s);
  dp[i + 64] = f2bf(x1 * c + x0 * s);
}

// ---------------- V transpose ----------------
__global__ __launch_bounds__(256) void vt_kernel(
    const u16* __restrict__ src, u16* __restrict__ vt) {
  __shared__ u16 tile[32][33];
  int s0 = blockIdx.x * 32;
  int d0 = blockIdx.y * 32;
  int bz = blockIdx.z;
  int b = bz >> 3, kvh = bz & 7;
  int tx = threadIdx.x, ty = threadIdx.y;
#pragma unroll
  for (int j = 0; j < 4; ++j)
    tile[ty + j * 8][tx] =
        src[(size_t)(b * 2048 + s0 + ty + j * 8) * 6144 + 5120 + kvh * 128 + d0 + tx];
  __syncthreads();
#pragma unroll
  for (int j = 0; j < 4; ++j)
    vt[((size_t)(b * 8 + kvh) * 128 + d0 + ty + j * 8) * 2048 + s0 + tx] =
        tile[tx][ty + j * 8];
}

// ---------------- Flash attention (causal, GQA) ----------------
// Balanced pairing: block p handles q-tiles (15-p) then (p): uniform 34 kv-steps.
// T14 reg-staging: issue next tile's global loads before compute, ds_write after
// barrier; raw s_barrier + lgkmcnt(0) only (no vmcnt(0) drain on the barrier path).
#define PS_LD 76

__device__ __forceinline__ void load_q_frag(short8 (&qf)[2][4], const u16* __restrict__ Q,
                                            int b, int q0, int w, int lq, int qd, int h) {
  const u16* qp = Q + ((size_t)(b * 2048 + q0 + w * 32 + lq) * 4096 + h * 128 + qd * 8);
#pragma unroll
  for (int n = 0; n < 2; ++n)
#pragma unroll
    for (int ks = 0; ks < 4; ++ks)
      qf[n][ks] = *(const short8*)(qp + (size_t)n * 16 * 4096 + ks * 32);
}

__device__ __forceinline__ void store_o(u16* __restrict__ O, const f32x4 (&ot)[2][8],
                                        const float* lsum, int b, int q0,
                                        int w, int lq, int qd, int h) {
#pragma unroll
  for (int n = 0; n < 2; ++n) {
    const float inv = 1.f / lsum[n];
    const size_t row = (size_t)(b * 2048 + q0 + w * 32 + n * 16 + lq);
    u16* op = O + row * 4096 + h * 128 + qd * 4;
#pragma unroll
    for (int mt = 0; mt < 8; ++mt) {
      u32 a = pack_bf2(ot[n][mt][0] * inv, ot[n][mt][1] * inv);
      u32 c = pack_bf2(ot[n][mt][2] * inv, ot[n][mt][3] * inv);
      *(uint2*)(op + mt * 16) = make_uint2(a, c);
    }
  }
}

__global__ __launch_bounds__(256, 2) void flash_kernel(
    const u16* __restrict__ Q, const u16* __restrict__ K,
    const u16* __restrict__ Vt, u16* __restrict__ O) {
  __shared__ alignas(16) u16 Ks[64 * 128];     // [kv][d] swizzled (key = row&7)
  __shared__ alignas(16) u16 Vs[128 * 64];     // [d][kv] swizzled (key = row&7)
  __shared__ alignas(16) u16 Ps[4][32 * PS_LD];

  const int tid = threadIdx.x;
  const int w = tid >> 6, lane = tid & 63;
  const int lq = lane & 15, qd = lane >> 4;
  const int lq7 = lq & 7;
  const int bh = blockIdx.y;
  const int b = bh >> 5, h = bh & 31, kvh = h >> 2;
  const int p = blockIdx.x;
  const int nhi = 32 - 2 * p;     // kv tiles for q-tile (15-p)
  const int nlo = 2 * p + 2;      // kv tiles for q-tile (p)
  const int nsteps = nhi + nlo;   // = 34 for every block

  // per-lane staging addresses (identical layout to the gl2lds version)
  const int rk = lane >> 4, pk = lane & 15;
  const int ckA = (pk ^ rk) * 8, ckB = (pk ^ (4 + rk)) * 8;
  const int rv = lane >> 3;
  const int cv = ((lane & 7) ^ rv) * 8;

  const u16* ksrc = K + ((size_t)(b * 2048 + w * 16 + rk) * 1024) + kvh * 128;
  const u16* vsrc = Vt + ((size_t)((b * 8 + kvh) * 128 + w * 32 + rv) * 2048) + cv;
  u16* kdst = &Ks[(w * 16) * 128] + lane * 8;  // +512 per 4-row group
  u16* vdst = &Vs[(w * 32) * 64] + lane * 8;   // +512 per 8-row group

  int q0 = (15 - p) * 128;
  short8 qf[2][4];
  load_q_frag(qf, Q, b, q0, w, lq, qd, h);

  f32x4 ot[2][8] = {};
  float mprev[2] = {-1e30f, -1e30f}, lsum[2] = {0.f, 0.f};

  uint4 kreg[4], vreg[4];
  // prologue: stage step 0 (kv0 = 0)
  kreg[0] = *(const uint4*)(ksrc + ckA);
  kreg[1] = *(const uint4*)(ksrc + 4096 + ckB);
  kreg[2] = *(const uint4*)(ksrc + 8192 + ckA);
  kreg[3] = *(const uint4*)(ksrc + 12288 + ckB);
  vreg[0] = *(const uint4*)(vsrc);
  vreg[1] = *(const uint4*)(vsrc + 8 * 2048);
  vreg[2] = *(const uint4*)(vsrc + 16 * 2048);
  vreg[3] = *(const uint4*)(vsrc + 24 * 2048);
  *(uint4*)(kdst) = kreg[0];
  *(uint4*)(kdst + 512) = kreg[1];
  *(uint4*)(kdst + 1024) = kreg[2];
  *(uint4*)(kdst + 1536) = kreg[3];
  *(uint4*)(vdst) = vreg[0];
  *(uint4*)(vdst + 512) = vreg[1];
  *(uint4*)(vdst + 1024) = vreg[2];
  *(uint4*)(vdst + 1536) = vreg[3];
  asm volatile("s_waitcnt lgkmcnt(0)" ::: "memory");
  __builtin_amdgcn_s_barrier();

  for (int s = 0; s < nsteps; ++s) {
    const int kv0 = (s < nhi ? s : s - nhi) * 64;

    // T14: issue next tile's global loads now; latency hides under compute
    if (s + 1 < nsteps) {
      const int sn = s + 1;
      const int kv0n = (sn < nhi ? sn : sn - nhi) * 64;
      const u16* kp_ = ksrc + (size_t)kv0n * 1024;
      kreg[0] = *(const uint4*)(kp_ + ckA);
      kreg[1] = *(const uint4*)(kp_ + 4096 + ckB);
      kreg[2] = *(const uint4*)(kp_ + 8192 + ckA);
      kreg[3] = *(const uint4*)(kp_ + 12288 + ckB);
      const u16* vp_ = vsrc + kv0n;
      vreg[0] = *(const uint4*)(vp_);
      vreg[1] = *(const uint4*)(vp_ + 8 * 2048);
      vreg[2] = *(const uint4*)(vp_ + 16 * 2048);
      vreg[3] = *(const uint4*)(vp_ + 24 * 2048);
    }

    // ---- QK^T ----
    f32x4 st[4][2] = {};
#pragma unroll
    for (int ks = 0; ks < 4; ++ks) {
      short8 kf[4];
#pragma unroll
      for (int m = 0; m < 4; ++m)
        kf[m] = *(const short8*)&Ks[(m * 16 + lq) * 128 + ((ks * 4 + qd) ^ lq7) * 8];
      __builtin_amdgcn_s_setprio(1);
#pragma unroll
      for (int m = 0; m < 4; ++m)
#pragma unroll
        for (int n = 0; n < 2; ++n)
          st[m][n] = mfma_bf16(kf[m], qf[n][ks], st[m][n]);
      __builtin_amdgcn_s_setprio(0);
    }

    if (kv0 + 63 > q0) {
#pragma unroll
      for (int n = 0; n < 2; ++n) {
        const int qrow = q0 + w * 32 + n * 16 + lq;
#pragma unroll
        for (int m = 0; m < 4; ++m) {
          const int kvb = kv0 + m * 16 + qd * 4;
#pragma unroll
          for (int r = 0; r < 4; ++r)
            if (kvb + r > qrow) st[m][n][r] = -1e30f;
        }
      }
    }

    // ---- online softmax ----
#pragma unroll
    for (int n = 0; n < 2; ++n) {
      float t = st[0][n][0];
#pragma unroll
      for (int m = 0; m < 4; ++m)
#pragma unroll
        for (int r = 0; r < 4; ++r) t = fmaxf(t, st[m][n][r]);
      t = fmaxf(t, __shfl_xor(t, 16));
      t = fmaxf(t, __shfl_xor(t, 32));
      const float mnew = fmaxf(mprev[n], t);
      const float alpha = __expf(mprev[n] - mnew);
      mprev[n] = mnew;

      float rs = 0.f;
      u32 pk2[4][2];
#pragma unroll
      for (int m = 0; m < 4; ++m) {
        float p0 = __expf(st[m][n][0] - mnew);
        float p1 = __expf(st[m][n][1] - mnew);
        float p2 = __expf(st[m][n][2] - mnew);
        float p3 = __expf(st[m][n][3] - mnew);
        rs += (p0 + p1) + (p2 + p3);
        pk2[m][0] = pack_bf2(p0, p1);
        pk2[m][1] = pack_bf2(p2, p3);
      }
      rs += __shfl_xor(rs, 16);
      rs += __shfl_xor(rs, 32);
      lsum[n] = lsum[n] * alpha + rs;

      u16* pw = &Ps[w][(n * 16 + lq) * PS_LD + qd * 4];
#pragma unroll
      for (int m = 0; m < 4; ++m)
        *(uint2*)(pw + m * 16) = make_uint2(pk2[m][0], pk2[m][1]);

#pragma unroll
      for (int mt = 0; mt < 8; ++mt)
#pragma unroll
        for (int r = 0; r < 4; ++r) ot[n][mt][r] *= alpha;
    }

    // ---- PV ----
#pragma unroll
    for (int kst = 0; kst < 2; ++kst) {
      short8 bp[2];
#pragma unroll
      for (int n = 0; n < 2; ++n)
        bp[n] = *(const short8*)&Ps[w][(n * 16 + lq) * PS_LD + kst * 32 + qd * 8];
#pragma unroll
      for (int mt = 0; mt < 8; ++mt) {
        short8 av = *(const short8*)&Vs[(mt * 16 + lq) * 64 + ((kst * 4 + qd) ^ lq7) * 8];
        __builtin_amdgcn_s_setprio(1);
#pragma unroll
        for (int n = 0; n < 2; ++n)
          ot[n][mt] = mfma_bf16(av, bp[n], ot[n][mt]);
        __builtin_amdgcn_s_setprio(0);
      }
    }

    // ---- barrier 1: all waves done reading LDS ----
    asm volatile("s_waitcnt lgkmcnt(0)" ::: "memory");
    __builtin_amdgcn_s_barrier();

    // ---- write staged regs -> LDS, barrier 2 ----
    if (s + 1 < nsteps) {
      *(uint4*)(kdst) = kreg[0];
      *(uint4*)(kdst + 512) = kreg[1];
      *(uint4*)(kdst + 1024) = kreg[2];
      *(uint4*)(kdst + 1536) = kreg[3];
      *(uint4*)(vdst) = vreg[0];
      *(uint4*)(vdst + 512) = vreg[1];
      *(uint4*)(vdst + 1024) = vreg[2];
      *(uint4*)(vdst + 1536) = vreg[3];
      asm volatile("s_waitcnt lgkmcnt(0)" ::: "memory");
      __builtin_amdgcn_s_barrier();
    }

    // ---- phase switch: finished hi tile, start lo tile ----
    if (s == nhi - 1) {
      store_o(O, ot, lsum, b, q0, w, lq, qd, h);
      q0 = p * 128;
      load_q_frag(qf, Q, b, q0, w, lq, qd, h);
#pragma unroll
      for (int n = 0; n < 2; ++n) {
        mprev[n] = -1e30f;
        lsum[n] = 0.f;
#pragma unroll
        for (int mt = 0; mt < 8; ++mt)
#pragma unroll
          for (int r = 0; r < 4; ++r) ot[n][mt][r] = 0.f;
      }
    }
  }

  store_o(O, ot, lsum, b, q0, w, lq, qd, h);
}

// ---------------- launcher ----------------
extern "C" void kernel_launch(void* const* d_in, const int* in_sizes, int n_in,
                              void* d_out, int out_size, void* d_ws, size_t ws_size,
                              hipStream_t stream) {
  const float* hidden = (const float*)d_in[0];
  const int* pos = (const int*)d_in[1];
  const float* Wq = (const float*)d_in[2];
  const float* Wk = (const float*)d_in[3];
  const float* Wv = (const float*)d_in[4];
  const float* Wo = (const float*)d_in[5];
  float* out = (float*)d_out;

  char* ws = (char*)d_ws;
  u16* hbf   = (u16*)(ws);                       // 4096x4096 bf16     (32 MiB)
  u16* wqkvt = (u16*)(ws + 33554432ull);         // 6144x4096 bf16 B^T (48 MiB)
  u16* wot   = (u16*)(ws + 83886080ull);         // 4096x4096 bf16 B^T (32 MiB)
  u16* qkvbf = (u16*)(ws + 117440512ull);        // 4096x6144 bf16     (48 MiB)
  u16* qbf   = (u16*)(ws + 167772160ull);        // 4096x4096 bf16
  u16* kbf   = (u16*)(ws + 201326592ull);        // 4096x1024 bf16
  u16* vt    = (u16*)(ws + 209715200ull);        // 2x8x128x2048 bf16
  u16* obf   = (u16*)(ws + 218103808ull);        // 4096x4096 bf16 (ends at 240 MiB)

  f32_to_bf16_kernel<<<16384, 256, 0, stream>>>(hidden, hbf, 16777216);
  transpose_w_kernel<<<dim3(128, 128), dim3(32, 8), 0, stream>>>(Wq, wqkvt, 4096, 4096);
  transpose_w_kernel<<<dim3(32, 128), dim3(32, 8), 0, stream>>>(Wk, wqkvt + (size_t)4096 * 4096, 4096, 1024);
  transpose_w_kernel<<<dim3(32, 128), dim3(32, 8), 0, stream>>>(Wv, wqkvt + (size_t)5120 * 4096, 4096, 1024);
  transpose_w_kernel<<<dim3(128, 128), dim3(32, 8), 0, stream>>>(Wo, wot, 4096, 4096);

  gemm_bt_256<true><<<dim3(24, 16), 512, 0, stream>>>(hbf, wqkvt, nullptr, qkvbf, 4096, 6144);

  rope_kernel<<<32768, 256, 0, stream>>>(qkvbf, qbf, pos, 32, 0, 4096, 8388608, 0.08838834764831845f);
  rope_kernel<<<8192, 256, 0, stream>>>(qkvbf, kbf, pos, 8, 4096, 1024, 2097152, 1.0f);

  vt_kernel<<<dim3(64, 4, 16), dim3(32, 8), 0, stream>>>(qkvbf, vt);

  flash_kernel<<<dim3(8, 64), 256, 0, stream>>>(qbf, kbf, vt, obf);

  gemm_bt_256<false><<<dim3(16, 16), 512, 0, stream>>>(obf, wot, out, nullptr, 4096, 4096);
}